// Round 10
// baseline (340.463 us; speedup 1.0000x reference)
//
#include <hip/hip_runtime.h>

typedef __bf16 bf16_t;
typedef __bf16 bf16x8 __attribute__((ext_vector_type(8)));
typedef __bf16 bf16x4 __attribute__((ext_vector_type(4)));
typedef float f32x4 __attribute__((ext_vector_type(4)));
typedef unsigned int u32;
typedef u32 u32x2 __attribute__((ext_vector_type(2)));
typedef u32 u32x4 __attribute__((ext_vector_type(4)));

#define MFMA16(a, b, c) __builtin_amdgcn_mfma_f32_16x16x32_bf16(a, b, c, 0, 0, 0)

#if __has_builtin(__builtin_amdgcn_exp2f)
#define EXP2(x) __builtin_amdgcn_exp2f(x)
#else
#define EXP2(x) exp2f(x)
#endif

// Combined 4x4 quad-transpose step on a dword pair (R8-verified builtin path).
#if __has_builtin(__builtin_amdgcn_permlane32_swap) && __has_builtin(__builtin_amdgcn_permlane16_swap)
#define PERMSWAP(a, b)                                                     \
  do {                                                                     \
    u32x2 _r = __builtin_amdgcn_permlane32_swap((a), (b), false, false);   \
    u32x2 _s = __builtin_amdgcn_permlane16_swap(_r[0], _r[1], false, false); \
    (a) = _s[0];                                                           \
    (b) = _s[1];                                                           \
  } while (0)
#else
#define PERMSWAP(a, b)                                                     \
  do {                                                                     \
    asm("v_permlane32_swap_b32 %0, %1" : "+v"(b), "+v"(a));                \
    asm("v_permlane16_swap_b32 %0, %1" : "+v"(b), "+v"(a));                \
  } while (0)
#endif

__device__ __forceinline__ void g2l16(const void* g, void* l) {
  __builtin_amdgcn_global_load_lds(
      (__attribute__((address_space(1))) void*)g,
      (__attribute__((address_space(3))) void*)l, 16, 0, 0);
}

// ---------------- fp32 -> bf16 conversion ----------------
__global__ void cvt_f32_bf16(const float* __restrict__ in, bf16_t* __restrict__ out, int n4) {
  int i = blockIdx.x * blockDim.x + threadIdx.x;
  if (i >= n4) return;
  const float4 v = ((const float4*)in)[i];
  bf16x4 o;
  o[0] = (bf16_t)v.x; o[1] = (bf16_t)v.y; o[2] = (bf16_t)v.z; o[3] = (bf16_t)v.w;
  ((bf16x4*)out)[i] = o;
}

// ---------------- bias permute v2 (for swapped-QK attn) ----------------
// attn lane (lr,quad) of wave handling q-tile qt, window kb needs
//   bias[q = qt*16+lr][k = kb*128 + (2i+(j>>2))*16 + quad*4 + (j&3)]
// stored at relp[(h*64+qt)*16384 + kb*2048 + i*512 + lane*8 + j]  (prescaled
// by log2e, bf16). Each attn bias load = 64 lanes x 16B = 1KB contiguous.
__global__ void permute_rel(const float* __restrict__ rel, bf16_t* __restrict__ relp) {
  __shared__ bf16_t Tl[16][1032];
  const int blk = blockIdx.x;            // h*64 + qt
  const int h = blk >> 6, qt = blk & 63;
  const int t = threadIdx.x;
  const float LOG2E = 1.44269504f;
  const float* src = rel + ((size_t)h * 1024 + qt * 16) * 1024;
#pragma unroll
  for (int it = 0; it < 16; ++it) {
    const int fid = it * 256 + t;        // float4 index 0..4095
    const int row = fid >> 8, c4 = (fid & 255) * 4;
    const float4 v = *(const float4*)(src + (size_t)row * 1024 + c4);
    bf16x4 o;
    o[0] = (bf16_t)(v.x * LOG2E); o[1] = (bf16_t)(v.y * LOG2E);
    o[2] = (bf16_t)(v.z * LOG2E); o[3] = (bf16_t)(v.w * LOG2E);
    *(bf16x4*)&Tl[row][c4] = o;
  }
  __syncthreads();
  bf16_t* dst = relp + (size_t)blk * 16384;
#pragma unroll
  for (int s = 0; s < 8; ++s) {
    const int c = s * 256 + t;           // bf16x8-chunk 0..2047
    const int kb = c >> 8, i = (c >> 6) & 3, lane = c & 63;
    const int lr = lane & 15, quad = lane >> 4;
    bf16x8 o;
#pragma unroll
    for (int j = 0; j < 8; ++j) {
      const int k = kb * 128 + (2 * i + (j >> 2)) * 16 + quad * 4 + (j & 3);
      o[j] = Tl[lr][k];
    }
    *(bf16x8*)(dst + (size_t)c * 8) = o;
  }
}

// ---------------- V transpose: [bh][seq][32] -> [bh][32][seq] ----------------
__global__ void transpose_v(const bf16_t* __restrict__ Vb, bf16_t* __restrict__ Vtb) {
  __shared__ bf16_t T[64][40];
  const int bh = blockIdx.y, s0 = blockIdx.x * 64;
  const int r = threadIdx.x >> 2, c8 = (threadIdx.x & 3) * 8;
  const bf16x8 v = *(const bf16x8*)(Vb + ((size_t)bh * 1024 + s0 + r) * 32 + c8);
#pragma unroll
  for (int j = 0; j < 8; ++j) T[r][c8 + j] = v[j];
  __syncthreads();
  const int d = threadIdx.x >> 3, q8 = (threadIdx.x & 7) * 8;
  bf16x8 o;
#pragma unroll
  for (int j = 0; j < 8; ++j) o[j] = T[q8 + j][d];
  *(bf16x8*)(Vtb + ((size_t)bh * 32 + d) * 1024 + s0 + q8) = o;
}

// ---------------- NT GEMM v2 (R9): 2-phase double-buffered staging ----------------
// R9 verdict: NEUTRAL vs the serial-staging form — block-level interleave was
// already masking staging latency. Kept (harmless, one fewer barrier/iter).
// MODE 0: A row-major [M][K]; epilogue scatters to Q(scaled)/K/V bf16.
// MODE 1: A is head-major [B*24][1024][32] (attention O); fp32 C store.
template <int MODE>
__global__ __launch_bounds__(256, 2) void gemm_bt(
    const bf16_t* __restrict__ A, const bf16_t* __restrict__ Bw,
    const float* __restrict__ bias, float* __restrict__ Cout,
    bf16_t* __restrict__ Qb, bf16_t* __restrict__ Kb, bf16_t* __restrict__ Vb,
    int M, int N, int K) {
  __shared__ bf16_t As[2][128 * 32];
  __shared__ bf16_t Bs[2][128 * 32];
  const int tid = threadIdx.x;
  const int wave = tid >> 6, lane = tid & 63, quad = lane >> 4, lr = lane & 15;
  const int bm = blockIdx.x * 128, bn = blockIdx.y * 128;
  const int wm = (wave >> 1) * 64, wn = (wave & 1) * 64;

  f32x4 acc[4][4] = {};

  const bf16_t* Ag;
  size_t strideA64;  // address delta for +64 rows
  if (MODE == 0) {
    Ag = A + (size_t)(bm + (tid >> 2)) * K + (tid & 3) * 8;
    strideA64 = (size_t)64 * K;
  } else {
    const int rr = bm + (tid >> 2);
    const int bidx = rr >> 10, seq = rr & 1023;
    Ag = A + ((size_t)bidx * 24 * 1024 + seq) * 32 + (tid & 3) * 8;
    strideA64 = (size_t)64 * 32;  // +64 seq rows, same batch
  }
  const bf16_t* Bg = Bw + (size_t)(bn + (tid >> 2)) * K + (tid & 3) * 8;
  const size_t strideB64 = (size_t)64 * K;

  auto stage = [&](int k0, int sel) {
    const size_t aoff = (MODE == 0) ? (size_t)k0 : (size_t)(k0 >> 5) * 32768;
    g2l16(Ag + aoff, &As[sel][tid * 8]);
    g2l16(Ag + strideA64 + aoff, &As[sel][tid * 8 + 2048]);
    g2l16(Bg + k0, &Bs[sel][tid * 8]);
    g2l16(Bg + strideB64 + k0, &Bs[sel][tid * 8 + 2048]);
  };

  const int NT = K >> 5;
  stage(0, 0);
  __syncthreads();  // drain initial staging
  for (int t = 0; t < NT; ++t) {
    const int sel = t & 1;
    if (t + 1 < NT) stage((t + 1) * 32, sel ^ 1);  // prefetch next K-step
    bf16x8 af[4], bfr[4];
#pragma unroll
    for (int i = 0; i < 4; ++i)
      af[i] = *(const bf16x8*)(&As[sel][(wm + i * 16 + lr) * 32 + quad * 8]);
#pragma unroll
    for (int j = 0; j < 4; ++j)
      bfr[j] = *(const bf16x8*)(&Bs[sel][(wn + j * 16 + lr) * 32 + quad * 8]);
#pragma unroll
    for (int i = 0; i < 4; ++i)
#pragma unroll
      for (int j = 0; j < 4; ++j)
        acc[i][j] = MFMA16(af[i], bfr[j], acc[i][j]);
    __syncthreads();  // drains prefetch vmcnt + this tile's lgkm; releases sel
  }

#pragma unroll
  for (int i = 0; i < 4; ++i) {
    const int row = bm + wm + i * 16 + quad * 4;
#pragma unroll
    for (int j = 0; j < 4; ++j) {
      const int col = bn + wn + j * 16 + lr;
      const float bb = bias[col];
#pragma unroll
      for (int r = 0; r < 4; ++r) {
        const float v = acc[i][j][r] + bb;
        const int rr = row + r;
        if (MODE == 1) {
          Cout[(size_t)rr * N + col] = v;
        } else {
          const int b = rr >> 10, seq = rr & 1023;
          const int head = col / 96, w = col % 96;
          const int bh = b * 24 + head;
          if (w < 32) {
            Qb[((size_t)bh * 1024 + seq) * 32 + w] = (bf16_t)(v * 0.17677669529663687f);
          } else if (w < 64) {
            Kb[((size_t)bh * 1024 + seq) * 32 + (w - 32)] = (bf16_t)v;
          } else {
            Vb[((size_t)bh * 1024 + seq) * 32 + (w - 64)] = (bf16_t)v;
          }
        }
      }
    }
  }
}

// ---------------- flash attention v16: 5 blocks/CU ----------------
// R10: occupancy was capped by the (256,4) launch bound, not by resources:
// LDS 32KB/block allows 5 blocks/CU (160/32); VGPR natural use is 56 vs a
// (256,5) budget of 102 — ~2x headroom, so no spill risk (unlike R1/R3
// where the forced budget was BELOW natural use). VALU is the top pipe at
// only 60% busy; a 5th resident block adds issue-side TLP.
__global__ __launch_bounds__(256, 5) void attn_flash(
    const bf16_t* __restrict__ Qb, const bf16_t* __restrict__ Kb,
    const bf16_t* __restrict__ Vtb, const bf16_t* __restrict__ relp,
    bf16_t* __restrict__ Ob) {
  __shared__ bf16_t Ks[2][128 * 32];
  __shared__ bf16_t Vs[2][32 * 128];

  const int tid = threadIdx.x;
  const int wave = tid >> 6, lane = tid & 63, quad = lane >> 4, lr = lane & 15;

  const int flat = blockIdx.x;
  const int xcd = flat & 7, slot = flat >> 3;
  const int pair = xcd + 8 * (slot >> 4);   // 0..191; same pair -> same XCD
  const int qi = slot & 15;
  const int b = pair / 24, h = pair % 24;
  const int bh = b * 24 + h;
  const int q0 = qi * 64 + wave * 16;
  const float LOG2E = 1.44269504f;

  const bf16x8 qf = *(const bf16x8*)(Qb + ((size_t)bh * 1024 + q0 + lr) * 32 + quad * 8);

  bf16x8 onesf;
#pragma unroll
  for (int i = 0; i < 8; ++i) onesf[i] = (bf16_t)1.0f;

  f32x4 o_acc[2] = {};
  f32x4 l_acc = {};  // row-sum accumulator: l = P * ones (MFMA pipe)

  // permuted bias v2: block = h*64 + (qi*4 + wave); per-lane 4x bf16x8
  const bf16_t* relg = relp + (size_t)(h * 64 + qi * 4 + wave) * 16384 + lane * 8;
  const bf16_t* Kg = Kb + (size_t)bh * 1024 * 32;
  const bf16_t* Vg = Vtb + (size_t)bh * 32 * 1024;

  // stage K-tile + Vt-tile for k-window [kt, kt+128) into buffer sel
  auto stageKV = [&](int kt, int sel) {
#pragma unroll
    for (int p = 0; p < 2; ++p) {
      const int cid = p * 256 + tid;           // 0..511
      const int krow = cid >> 2, kc = cid & 3;
      const int ks_ = (krow >> 1) & 3;
      g2l16(Kg + ((size_t)(kt + krow) * 32 + ((kc ^ ks_) * 8)), &Ks[sel][cid * 8]);
      const int vd = cid >> 4, vc = cid & 15;
      g2l16(Vg + ((size_t)vd * 1024 + kt + ((vc ^ (vd & 7)) * 8)), &Vs[sel][cid * 8]);
    }
  };

  auto body = [&](int kt, int sel) {
    // bias tile: 4x bf16x8, 1KB contiguous per wave-load
    bf16x8 bb[4];
    const bf16_t* rb = relg + (size_t)(kt >> 7) * 2048;
#pragma unroll
    for (int i = 0; i < 4; ++i) bb[i] = *(const bf16x8*)(rb + i * 512);

    // S^T = K Q^T (swapped): lane holds q = lr, k = jt*16 + quad*4 + r
    f32x4 s[8];
    const f32x4 zz = {0.f, 0.f, 0.f, 0.f};
    const int kcs = quad ^ ((lr >> 1) & 3);   // staged-K chunk swizzle
#pragma unroll
    for (int jt = 0; jt < 8; ++jt) {
      const bf16x8 kf = *(const bf16x8*)&Ks[sel][(jt * 16 + lr) * 32 + kcs * 8];
      s[jt] = MFMA16(kf, qf, zz);
    }
    // P = exp2(S*log2e + bias_prescaled); bias (jt,r) = bb[jt>>1][(jt&1)*4+r]
#pragma unroll
    for (int jt = 0; jt < 8; ++jt)
#pragma unroll
      for (int r = 0; r < 4; ++r)
        s[jt][r] = EXP2(fmaf(s[jt][r], LOG2E, (float)bb[jt >> 1][(jt & 1) * 4 + r]));

    // P -> PV A-frag entirely in registers (permlane 4x4 quad-transpose)
#pragma unroll
    for (int ks = 0; ks < 4; ++ks) {
      bf16x4 pe, po;
#pragma unroll
      for (int r = 0; r < 4; ++r) {
        pe[r] = (bf16_t)s[2 * ks][r];
        po[r] = (bf16_t)s[2 * ks + 1][r];
      }
      u32x2 ue = __builtin_bit_cast(u32x2, pe);
      u32x2 uo = __builtin_bit_cast(u32x2, po);
      u32 d0 = ue[0], d1 = ue[1], d2 = uo[0], d3 = uo[1];
      PERMSWAP(d0, d2);
      PERMSWAP(d1, d3);
      u32x4 uf = {d0, d1, d2, d3};
      const bf16x8 pf = __builtin_bit_cast(bf16x8, uf);

      l_acc = MFMA16(pf, onesf, l_acc);
#pragma unroll
      for (int nt = 0; nt < 2; ++nt) {
        const int d = nt * 16 + lr;
        const int vc = (ks * 4 + quad) ^ (d & 7);
        const bf16x8 vf = *(const bf16x8*)&Vs[sel][d * 128 + vc * 8];
        o_acc[nt] = MFMA16(pf, vf, o_acc[nt]);
      }
    }
  };

  stageKV(0, 0);
  __syncthreads();  // drains staging vmcnt
  for (int t = 0; t < 8; ++t) {
    const int sel = t & 1;
    if (t < 7) stageKV((t + 1) * 128, sel ^ 1);  // prefetch next tile
    body(t * 128, sel);                          // compute current tile
    __syncthreads();
  }

  // write O head-major [bh][seq][32] — packed stores
  float inv_l[4];
#pragma unroll
  for (int r = 0; r < 4; ++r) inv_l[r] = 1.0f / l_acc[r];
#pragma unroll
  for (int nt = 0; nt < 2; ++nt)
#pragma unroll
    for (int r = 0; r < 4; ++r) {
      const int seq = q0 + quad * 4 + r;
      Ob[((size_t)bh * 1024 + seq) * 32 + nt * 16 + lr] = (bf16_t)(o_acc[nt][r] * inv_l[r]);
    }
}

extern "C" void kernel_launch(void* const* d_in, const int* in_sizes, int n_in,
                              void* d_out, int out_size, void* d_ws, size_t ws_size,
                              hipStream_t stream) {
  const float* x = (const float*)d_in[0];
  const float* rel = (const float*)d_in[1];
  const float* Wqkv = (const float*)d_in[2];
  const float* bqkv = (const float*)d_in[3];
  const float* Wproj = (const float*)d_in[4];
  const float* bproj = (const float*)d_in[5];
  float* out = (float*)d_out;

  char* ws = (char*)d_ws;
  bf16_t* xb = (bf16_t*)ws;     ws += (size_t)8192 * 768 * 2;
  bf16_t* wqkvb = (bf16_t*)ws;  ws += (size_t)2304 * 768 * 2;
  bf16_t* wprojb = (bf16_t*)ws; ws += (size_t)768 * 768 * 2;
  bf16_t* Qb = (bf16_t*)ws;     ws += (size_t)192 * 1024 * 32 * 2;
  bf16_t* Kb = (bf16_t*)ws;     ws += (size_t)192 * 1024 * 32 * 2;
  bf16_t* Vb = (bf16_t*)ws;     ws += (size_t)192 * 1024 * 32 * 2;
  bf16_t* Vtb = (bf16_t*)ws;    ws += (size_t)192 * 1024 * 32 * 2;
  bf16_t* relp = (bf16_t*)ws;   ws += (size_t)24 * 1024 * 1024 * 2;
  bf16_t* Ob = xb;  // xb dead after QKV GEMM; O is head-major [bh][seq][32]

  cvt_f32_bf16<<<(8192 * 768 / 4 + 255) / 256, 256, 0, stream>>>(x, xb, 8192 * 768 / 4);
  cvt_f32_bf16<<<(2304 * 768 / 4 + 255) / 256, 256, 0, stream>>>(Wqkv, wqkvb, 2304 * 768 / 4);
  cvt_f32_bf16<<<(768 * 768 / 4 + 255) / 256, 256, 0, stream>>>(Wproj, wprojb, 768 * 768 / 4);
  permute_rel<<<dim3(24 * 64), 256, 0, stream>>>(rel, relp);

  gemm_bt<0><<<dim3(64, 18), 256, 0, stream>>>(xb, wqkvb, bqkv, nullptr,
                                               Qb, Kb, Vb, 8192, 2304, 768);
  transpose_v<<<dim3(16, 192), 256, 0, stream>>>(Vb, Vtb);
  attn_flash<<<dim3(3072), 256, 0, stream>>>(Qb, Kb, Vtb, relp, Ob);
  gemm_bt<1><<<dim3(64, 6), 256, 0, stream>>>(Ob, wprojb, bproj, out,
                                              nullptr, nullptr, nullptr, 8192, 768, 768);
}

// Round 11
// 329.281 us; speedup vs baseline: 1.0340x; 1.0340x over previous
//
#include <hip/hip_runtime.h>

typedef __bf16 bf16_t;
typedef __bf16 bf16x8 __attribute__((ext_vector_type(8)));
typedef __bf16 bf16x4 __attribute__((ext_vector_type(4)));
typedef float f32x4 __attribute__((ext_vector_type(4)));
typedef unsigned int u32;
typedef u32 u32x2 __attribute__((ext_vector_type(2)));
typedef u32 u32x4 __attribute__((ext_vector_type(4)));

#define MFMA16(a, b, c) __builtin_amdgcn_mfma_f32_16x16x32_bf16(a, b, c, 0, 0, 0)

#if __has_builtin(__builtin_amdgcn_exp2f)
#define EXP2(x) __builtin_amdgcn_exp2f(x)
#else
#define EXP2(x) exp2f(x)
#endif

// Combined 4x4 quad-transpose step on a dword pair (R8-verified builtin path).
#if __has_builtin(__builtin_amdgcn_permlane32_swap) && __has_builtin(__builtin_amdgcn_permlane16_swap)
#define PERMSWAP(a, b)                                                     \
  do {                                                                     \
    u32x2 _r = __builtin_amdgcn_permlane32_swap((a), (b), false, false);   \
    u32x2 _s = __builtin_amdgcn_permlane16_swap(_r[0], _r[1], false, false); \
    (a) = _s[0];                                                           \
    (b) = _s[1];                                                           \
  } while (0)
#else
#define PERMSWAP(a, b)                                                     \
  do {                                                                     \
    asm("v_permlane32_swap_b32 %0, %1" : "+v"(b), "+v"(a));                \
    asm("v_permlane16_swap_b32 %0, %1" : "+v"(b), "+v"(a));                \
  } while (0)
#endif

__device__ __forceinline__ void g2l16(const void* g, void* l) {
  __builtin_amdgcn_global_load_lds(
      (__attribute__((address_space(1))) void*)g,
      (__attribute__((address_space(3))) void*)l, 16, 0, 0);
}

// ---------------- fp32 -> bf16 conversion ----------------
__global__ void cvt_f32_bf16(const float* __restrict__ in, bf16_t* __restrict__ out, int n4) {
  int i = blockIdx.x * blockDim.x + threadIdx.x;
  if (i >= n4) return;
  const float4 v = ((const float4*)in)[i];
  bf16x4 o;
  o[0] = (bf16_t)v.x; o[1] = (bf16_t)v.y; o[2] = (bf16_t)v.z; o[3] = (bf16_t)v.w;
  ((bf16x4*)out)[i] = o;
}

// ---------------- bias permute v2 (for swapped-QK attn) ----------------
// attn lane (lr,quad) of wave handling q-tile qt, window kb needs
//   bias[q = qt*16+lr][k = kb*128 + (2i+(j>>2))*16 + quad*4 + (j&3)]
// stored at relp[(h*64+qt)*16384 + kb*2048 + i*512 + lane*8 + j]  (prescaled
// by log2e, bf16). Each attn bias load = 64 lanes x 16B = 1KB contiguous.
__global__ void permute_rel(const float* __restrict__ rel, bf16_t* __restrict__ relp) {
  __shared__ bf16_t Tl[16][1032];
  const int blk = blockIdx.x;            // h*64 + qt
  const int h = blk >> 6, qt = blk & 63;
  const int t = threadIdx.x;
  const float LOG2E = 1.44269504f;
  const float* src = rel + ((size_t)h * 1024 + qt * 16) * 1024;
#pragma unroll
  for (int it = 0; it < 16; ++it) {
    const int fid = it * 256 + t;        // float4 index 0..4095
    const int row = fid >> 8, c4 = (fid & 255) * 4;
    const float4 v = *(const float4*)(src + (size_t)row * 1024 + c4);
    bf16x4 o;
    o[0] = (bf16_t)(v.x * LOG2E); o[1] = (bf16_t)(v.y * LOG2E);
    o[2] = (bf16_t)(v.z * LOG2E); o[3] = (bf16_t)(v.w * LOG2E);
    *(bf16x4*)&Tl[row][c4] = o;
  }
  __syncthreads();
  bf16_t* dst = relp + (size_t)blk * 16384;
#pragma unroll
  for (int s = 0; s < 8; ++s) {
    const int c = s * 256 + t;           // bf16x8-chunk 0..2047
    const int kb = c >> 8, i = (c >> 6) & 3, lane = c & 63;
    const int lr = lane & 15, quad = lane >> 4;
    bf16x8 o;
#pragma unroll
    for (int j = 0; j < 8; ++j) {
      const int k = kb * 128 + (2 * i + (j >> 2)) * 16 + quad * 4 + (j & 3);
      o[j] = Tl[lr][k];
    }
    *(bf16x8*)(dst + (size_t)c * 8) = o;
  }
}

// ---------------- V transpose: [bh][seq][32] -> [bh][32][seq] ----------------
__global__ void transpose_v(const bf16_t* __restrict__ Vb, bf16_t* __restrict__ Vtb) {
  __shared__ bf16_t T[64][40];
  const int bh = blockIdx.y, s0 = blockIdx.x * 64;
  const int r = threadIdx.x >> 2, c8 = (threadIdx.x & 3) * 8;
  const bf16x8 v = *(const bf16x8*)(Vb + ((size_t)bh * 1024 + s0 + r) * 32 + c8);
#pragma unroll
  for (int j = 0; j < 8; ++j) T[r][c8 + j] = v[j];
  __syncthreads();
  const int d = threadIdx.x >> 3, q8 = (threadIdx.x & 7) * 8;
  bf16x8 o;
#pragma unroll
  for (int j = 0; j < 8; ++j) o[j] = T[q8 + j][d];
  *(bf16x8*)(Vtb + ((size_t)bh * 32 + d) * 1024 + s0 + q8) = o;
}

// ---------------- NT GEMM v3: 2-phase double-buffer + 3 blocks/CU ----------------
// R11: the GEMM has run at 2 blocks/CU (8 waves/CU) all session — the lowest
// occupancy of any kernel here, and the one kernel never tuned for TLP (R9
// only changed its schedule, which proved already-masked). (256,3): VGPR
// budget 170 vs natural ~110 (acc 64 + frags 32 + addr) — no-spill headroom,
// unlike attn's R1/R3/R10 failures. LDS 32KB allows 5 blocks.
// MODE 0: A row-major [M][K]; epilogue scatters to Q(scaled)/K/V bf16.
// MODE 1: A is head-major [B*24][1024][32] (attention O); fp32 C store.
template <int MODE>
__global__ __launch_bounds__(256, 3) void gemm_bt(
    const bf16_t* __restrict__ A, const bf16_t* __restrict__ Bw,
    const float* __restrict__ bias, float* __restrict__ Cout,
    bf16_t* __restrict__ Qb, bf16_t* __restrict__ Kb, bf16_t* __restrict__ Vb,
    int M, int N, int K) {
  __shared__ bf16_t As[2][128 * 32];
  __shared__ bf16_t Bs[2][128 * 32];
  const int tid = threadIdx.x;
  const int wave = tid >> 6, lane = tid & 63, quad = lane >> 4, lr = lane & 15;
  const int bm = blockIdx.x * 128, bn = blockIdx.y * 128;
  const int wm = (wave >> 1) * 64, wn = (wave & 1) * 64;

  f32x4 acc[4][4] = {};

  const bf16_t* Ag;
  size_t strideA64;  // address delta for +64 rows
  if (MODE == 0) {
    Ag = A + (size_t)(bm + (tid >> 2)) * K + (tid & 3) * 8;
    strideA64 = (size_t)64 * K;
  } else {
    const int rr = bm + (tid >> 2);
    const int bidx = rr >> 10, seq = rr & 1023;
    Ag = A + ((size_t)bidx * 24 * 1024 + seq) * 32 + (tid & 3) * 8;
    strideA64 = (size_t)64 * 32;  // +64 seq rows, same batch
  }
  const bf16_t* Bg = Bw + (size_t)(bn + (tid >> 2)) * K + (tid & 3) * 8;
  const size_t strideB64 = (size_t)64 * K;

  auto stage = [&](int k0, int sel) {
    const size_t aoff = (MODE == 0) ? (size_t)k0 : (size_t)(k0 >> 5) * 32768;
    g2l16(Ag + aoff, &As[sel][tid * 8]);
    g2l16(Ag + strideA64 + aoff, &As[sel][tid * 8 + 2048]);
    g2l16(Bg + k0, &Bs[sel][tid * 8]);
    g2l16(Bg + strideB64 + k0, &Bs[sel][tid * 8 + 2048]);
  };

  const int NT = K >> 5;
  stage(0, 0);
  __syncthreads();  // drain initial staging
  for (int t = 0; t < NT; ++t) {
    const int sel = t & 1;
    if (t + 1 < NT) stage((t + 1) * 32, sel ^ 1);  // prefetch next K-step
    bf16x8 af[4], bfr[4];
#pragma unroll
    for (int i = 0; i < 4; ++i)
      af[i] = *(const bf16x8*)(&As[sel][(wm + i * 16 + lr) * 32 + quad * 8]);
#pragma unroll
    for (int j = 0; j < 4; ++j)
      bfr[j] = *(const bf16x8*)(&Bs[sel][(wn + j * 16 + lr) * 32 + quad * 8]);
#pragma unroll
    for (int i = 0; i < 4; ++i)
#pragma unroll
      for (int j = 0; j < 4; ++j)
        acc[i][j] = MFMA16(af[i], bfr[j], acc[i][j]);
    __syncthreads();  // drains prefetch vmcnt + this tile's lgkm; releases sel
  }

#pragma unroll
  for (int i = 0; i < 4; ++i) {
    const int row = bm + wm + i * 16 + quad * 4;
#pragma unroll
    for (int j = 0; j < 4; ++j) {
      const int col = bn + wn + j * 16 + lr;
      const float bb = bias[col];
#pragma unroll
      for (int r = 0; r < 4; ++r) {
        const float v = acc[i][j][r] + bb;
        const int rr = row + r;
        if (MODE == 1) {
          Cout[(size_t)rr * N + col] = v;
        } else {
          const int b = rr >> 10, seq = rr & 1023;
          const int head = col / 96, w = col % 96;
          const int bh = b * 24 + head;
          if (w < 32) {
            Qb[((size_t)bh * 1024 + seq) * 32 + w] = (bf16_t)(v * 0.17677669529663687f);
          } else if (w < 64) {
            Kb[((size_t)bh * 1024 + seq) * 32 + (w - 32)] = (bf16_t)v;
          } else {
            Vb[((size_t)bh * 1024 + seq) * 32 + (w - 64)] = (bf16_t)v;
          }
        }
      }
    }
  }
}

// ---------------- flash attention v15 (R8/R9-verified config) ----------------
// Occupancy ledger: (256,8) spill [R1], (256,6) spill [R3], (256,5)
// allocator-squeeze VGPR 56->44 + occupancy DIDN'T rise, -11% [R10].
// (256,4) / VGPR 56 is this kernel's fixed point. Knob retired.
__global__ __launch_bounds__(256, 4) void attn_flash(
    const bf16_t* __restrict__ Qb, const bf16_t* __restrict__ Kb,
    const bf16_t* __restrict__ Vtb, const bf16_t* __restrict__ relp,
    bf16_t* __restrict__ Ob) {
  __shared__ bf16_t Ks[2][128 * 32];
  __shared__ bf16_t Vs[2][32 * 128];

  const int tid = threadIdx.x;
  const int wave = tid >> 6, lane = tid & 63, quad = lane >> 4, lr = lane & 15;

  const int flat = blockIdx.x;
  const int xcd = flat & 7, slot = flat >> 3;
  const int pair = xcd + 8 * (slot >> 4);   // 0..191; same pair -> same XCD
  const int qi = slot & 15;
  const int b = pair / 24, h = pair % 24;
  const int bh = b * 24 + h;
  const int q0 = qi * 64 + wave * 16;
  const float LOG2E = 1.44269504f;

  const bf16x8 qf = *(const bf16x8*)(Qb + ((size_t)bh * 1024 + q0 + lr) * 32 + quad * 8);

  bf16x8 onesf;
#pragma unroll
  for (int i = 0; i < 8; ++i) onesf[i] = (bf16_t)1.0f;

  f32x4 o_acc[2] = {};
  f32x4 l_acc = {};  // row-sum accumulator: l = P * ones (MFMA pipe)

  // permuted bias v2: block = h*64 + (qi*4 + wave); per-lane 4x bf16x8
  const bf16_t* relg = relp + (size_t)(h * 64 + qi * 4 + wave) * 16384 + lane * 8;
  const bf16_t* Kg = Kb + (size_t)bh * 1024 * 32;
  const bf16_t* Vg = Vtb + (size_t)bh * 32 * 1024;

  // stage K-tile + Vt-tile for k-window [kt, kt+128) into buffer sel
  auto stageKV = [&](int kt, int sel) {
#pragma unroll
    for (int p = 0; p < 2; ++p) {
      const int cid = p * 256 + tid;           // 0..511
      const int krow = cid >> 2, kc = cid & 3;
      const int ks_ = (krow >> 1) & 3;
      g2l16(Kg + ((size_t)(kt + krow) * 32 + ((kc ^ ks_) * 8)), &Ks[sel][cid * 8]);
      const int vd = cid >> 4, vc = cid & 15;
      g2l16(Vg + ((size_t)vd * 1024 + kt + ((vc ^ (vd & 7)) * 8)), &Vs[sel][cid * 8]);
    }
  };

  auto body = [&](int kt, int sel) {
    // bias tile: 4x bf16x8, 1KB contiguous per wave-load
    bf16x8 bb[4];
    const bf16_t* rb = relg + (size_t)(kt >> 7) * 2048;
#pragma unroll
    for (int i = 0; i < 4; ++i) bb[i] = *(const bf16x8*)(rb + i * 512);

    // S^T = K Q^T (swapped): lane holds q = lr, k = jt*16 + quad*4 + r
    f32x4 s[8];
    const f32x4 zz = {0.f, 0.f, 0.f, 0.f};
    const int kcs = quad ^ ((lr >> 1) & 3);   // staged-K chunk swizzle
#pragma unroll
    for (int jt = 0; jt < 8; ++jt) {
      const bf16x8 kf = *(const bf16x8*)&Ks[sel][(jt * 16 + lr) * 32 + kcs * 8];
      s[jt] = MFMA16(kf, qf, zz);
    }
    // P = exp2(S*log2e + bias_prescaled); bias (jt,r) = bb[jt>>1][(jt&1)*4+r]
#pragma unroll
    for (int jt = 0; jt < 8; ++jt)
#pragma unroll
      for (int r = 0; r < 4; ++r)
        s[jt][r] = EXP2(fmaf(s[jt][r], LOG2E, (float)bb[jt >> 1][(jt & 1) * 4 + r]));

    // P -> PV A-frag entirely in registers (permlane 4x4 quad-transpose)
#pragma unroll
    for (int ks = 0; ks < 4; ++ks) {
      bf16x4 pe, po;
#pragma unroll
      for (int r = 0; r < 4; ++r) {
        pe[r] = (bf16_t)s[2 * ks][r];
        po[r] = (bf16_t)s[2 * ks + 1][r];
      }
      u32x2 ue = __builtin_bit_cast(u32x2, pe);
      u32x2 uo = __builtin_bit_cast(u32x2, po);
      u32 d0 = ue[0], d1 = ue[1], d2 = uo[0], d3 = uo[1];
      PERMSWAP(d0, d2);
      PERMSWAP(d1, d3);
      u32x4 uf = {d0, d1, d2, d3};
      const bf16x8 pf = __builtin_bit_cast(bf16x8, uf);

      l_acc = MFMA16(pf, onesf, l_acc);
#pragma unroll
      for (int nt = 0; nt < 2; ++nt) {
        const int d = nt * 16 + lr;
        const int vc = (ks * 4 + quad) ^ (d & 7);
        const bf16x8 vf = *(const bf16x8*)&Vs[sel][d * 128 + vc * 8];
        o_acc[nt] = MFMA16(pf, vf, o_acc[nt]);
      }
    }
  };

  stageKV(0, 0);
  __syncthreads();  // drains staging vmcnt
  for (int t = 0; t < 8; ++t) {
    const int sel = t & 1;
    if (t < 7) stageKV((t + 1) * 128, sel ^ 1);  // prefetch next tile
    body(t * 128, sel);                          // compute current tile
    __syncthreads();
  }

  // write O head-major [bh][seq][32] — packed stores
  float inv_l[4];
#pragma unroll
  for (int r = 0; r < 4; ++r) inv_l[r] = 1.0f / l_acc[r];
#pragma unroll
  for (int nt = 0; nt < 2; ++nt)
#pragma unroll
    for (int r = 0; r < 4; ++r) {
      const int seq = q0 + quad * 4 + r;
      Ob[((size_t)bh * 1024 + seq) * 32 + nt * 16 + lr] = (bf16_t)(o_acc[nt][r] * inv_l[r]);
    }
}

extern "C" void kernel_launch(void* const* d_in, const int* in_sizes, int n_in,
                              void* d_out, int out_size, void* d_ws, size_t ws_size,
                              hipStream_t stream) {
  const float* x = (const float*)d_in[0];
  const float* rel = (const float*)d_in[1];
  const float* Wqkv = (const float*)d_in[2];
  const float* bqkv = (const float*)d_in[3];
  const float* Wproj = (const float*)d_in[4];
  const float* bproj = (const float*)d_in[5];
  float* out = (float*)d_out;

  char* ws = (char*)d_ws;
  bf16_t* xb = (bf16_t*)ws;     ws += (size_t)8192 * 768 * 2;
  bf16_t* wqkvb = (bf16_t*)ws;  ws += (size_t)2304 * 768 * 2;
  bf16_t* wprojb = (bf16_t*)ws; ws += (size_t)768 * 768 * 2;
  bf16_t* Qb = (bf16_t*)ws;     ws += (size_t)192 * 1024 * 32 * 2;
  bf16_t* Kb = (bf16_t*)ws;     ws += (size_t)192 * 1024 * 32 * 2;
  bf16_t* Vb = (bf16_t*)ws;     ws += (size_t)192 * 1024 * 32 * 2;
  bf16_t* Vtb = (bf16_t*)ws;    ws += (size_t)192 * 1024 * 32 * 2;
  bf16_t* relp = (bf16_t*)ws;   ws += (size_t)24 * 1024 * 1024 * 2;
  bf16_t* Ob = xb;  // xb dead after QKV GEMM; O is head-major [bh][seq][32]

  cvt_f32_bf16<<<(8192 * 768 / 4 + 255) / 256, 256, 0, stream>>>(x, xb, 8192 * 768 / 4);
  cvt_f32_bf16<<<(2304 * 768 / 4 + 255) / 256, 256, 0, stream>>>(Wqkv, wqkvb, 2304 * 768 / 4);
  cvt_f32_bf16<<<(768 * 768 / 4 + 255) / 256, 256, 0, stream>>>(Wproj, wprojb, 768 * 768 / 4);
  permute_rel<<<dim3(24 * 64), 256, 0, stream>>>(rel, relp);

  gemm_bt<0><<<dim3(64, 18), 256, 0, stream>>>(xb, wqkvb, bqkv, nullptr,
                                               Qb, Kb, Vb, 8192, 2304, 768);
  transpose_v<<<dim3(16, 192), 256, 0, stream>>>(Vb, Vtb);
  attn_flash<<<dim3(3072), 256, 0, stream>>>(Qb, Kb, Vtb, relp, Ob);
  gemm_bt<1><<<dim3(64, 6), 256, 0, stream>>>(Ob, wprojb, bproj, out,
                                              nullptr, nullptr, nullptr, 8192, 768, 768);
}

// Round 12
// 325.717 us; speedup vs baseline: 1.0453x; 1.0109x over previous
//
#include <hip/hip_runtime.h>

typedef __bf16 bf16_t;
typedef __bf16 bf16x8 __attribute__((ext_vector_type(8)));
typedef __bf16 bf16x4 __attribute__((ext_vector_type(4)));
typedef float f32x4 __attribute__((ext_vector_type(4)));
typedef unsigned int u32;
typedef u32 u32x2 __attribute__((ext_vector_type(2)));
typedef u32 u32x4 __attribute__((ext_vector_type(4)));

#define MFMA16(a, b, c) __builtin_amdgcn_mfma_f32_16x16x32_bf16(a, b, c, 0, 0, 0)

#if __has_builtin(__builtin_amdgcn_exp2f)
#define EXP2(x) __builtin_amdgcn_exp2f(x)
#else
#define EXP2(x) exp2f(x)
#endif

// Combined 4x4 quad-transpose step on a dword pair (R8-verified builtin path).
#if __has_builtin(__builtin_amdgcn_permlane32_swap) && __has_builtin(__builtin_amdgcn_permlane16_swap)
#define PERMSWAP(a, b)                                                     \
  do {                                                                     \
    u32x2 _r = __builtin_amdgcn_permlane32_swap((a), (b), false, false);   \
    u32x2 _s = __builtin_amdgcn_permlane16_swap(_r[0], _r[1], false, false); \
    (a) = _s[0];                                                           \
    (b) = _s[1];                                                           \
  } while (0)
#else
#define PERMSWAP(a, b)                                                     \
  do {                                                                     \
    asm("v_permlane32_swap_b32 %0, %1" : "+v"(b), "+v"(a));                \
    asm("v_permlane16_swap_b32 %0, %1" : "+v"(b), "+v"(a));                \
  } while (0)
#endif

__device__ __forceinline__ void g2l16(const void* g, void* l) {
  __builtin_amdgcn_global_load_lds(
      (__attribute__((address_space(1))) void*)g,
      (__attribute__((address_space(3))) void*)l, 16, 0, 0);
}

// ---------------- fp32 -> bf16 conversion ----------------
__global__ void cvt_f32_bf16(const float* __restrict__ in, bf16_t* __restrict__ out, int n4) {
  int i = blockIdx.x * blockDim.x + threadIdx.x;
  if (i >= n4) return;
  const float4 v = ((const float4*)in)[i];
  bf16x4 o;
  o[0] = (bf16_t)v.x; o[1] = (bf16_t)v.y; o[2] = (bf16_t)v.z; o[3] = (bf16_t)v.w;
  ((bf16x4*)out)[i] = o;
}

// ---------------- bias permute v2 (for swapped-QK attn) ----------------
// attn lane (lr,quad) of wave handling q-tile qt, window kb needs
//   bias[q = qt*16+lr][k = kb*128 + (2i+(j>>2))*16 + quad*4 + (j&3)]
// stored at relp[(h*64+qt)*16384 + kb*2048 + i*512 + lane*8 + j]  (prescaled
// by log2e, bf16). Each attn bias load = 64 lanes x 16B = 1KB contiguous.
__global__ void permute_rel(const float* __restrict__ rel, bf16_t* __restrict__ relp) {
  __shared__ bf16_t Tl[16][1032];
  const int blk = blockIdx.x;            // h*64 + qt
  const int h = blk >> 6, qt = blk & 63;
  const int t = threadIdx.x;
  const float LOG2E = 1.44269504f;
  const float* src = rel + ((size_t)h * 1024 + qt * 16) * 1024;
#pragma unroll
  for (int it = 0; it < 16; ++it) {
    const int fid = it * 256 + t;        // float4 index 0..4095
    const int row = fid >> 8, c4 = (fid & 255) * 4;
    const float4 v = *(const float4*)(src + (size_t)row * 1024 + c4);
    bf16x4 o;
    o[0] = (bf16_t)(v.x * LOG2E); o[1] = (bf16_t)(v.y * LOG2E);
    o[2] = (bf16_t)(v.z * LOG2E); o[3] = (bf16_t)(v.w * LOG2E);
    *(bf16x4*)&Tl[row][c4] = o;
  }
  __syncthreads();
  bf16_t* dst = relp + (size_t)blk * 16384;
#pragma unroll
  for (int s = 0; s < 8; ++s) {
    const int c = s * 256 + t;           // bf16x8-chunk 0..2047
    const int kb = c >> 8, i = (c >> 6) & 3, lane = c & 63;
    const int lr = lane & 15, quad = lane >> 4;
    bf16x8 o;
#pragma unroll
    for (int j = 0; j < 8; ++j) {
      const int k = kb * 128 + (2 * i + (j >> 2)) * 16 + quad * 4 + (j & 3);
      o[j] = Tl[lr][k];
    }
    *(bf16x8*)(dst + (size_t)c * 8) = o;
  }
}

// ---------------- NT GEMM v4: swapped-operand epilogue + fused V transpose ----------------
// R12: acc computed as MFMA(bfr, af) => C^T fragment: lane (lr,quad) holds
// C[row = tile_m + lr][col = tile_n + quad*4 + s], s=0..3 — 4 CONSECUTIVE
// columns per lane. Epilogue consequences:
//  - Q/K: one 8B bf16x4 store per (i,j) tile (was 4 scalar b16 scatters).
//  - V: written DIRECTLY TRANSPOSED to Vtb[bh][d][seq] (4 scalar stores,
//    same count as the old Vb path) -> transpose_v kernel + Vb buffer and
//    their 25MB round trip are deleted.
//  - MODE 1: one float4 16B store per tile (was 4 dwords); float4 bias load.
// Region/head branch is wave-uniform: 16-wide, 16-aligned tiles never
// straddle the 32-wide Q/K/V regions or 96-wide heads (96%16==0).
// K-loop unchanged (R9 double-buffer, R11 (256,3) kept).
template <int MODE>
__global__ __launch_bounds__(256, 3) void gemm_bt(
    const bf16_t* __restrict__ A, const bf16_t* __restrict__ Bw,
    const float* __restrict__ bias, float* __restrict__ Cout,
    bf16_t* __restrict__ Qb, bf16_t* __restrict__ Kb, bf16_t* __restrict__ Vtb,
    int M, int N, int K) {
  __shared__ bf16_t As[2][128 * 32];
  __shared__ bf16_t Bs[2][128 * 32];
  const int tid = threadIdx.x;
  const int wave = tid >> 6, lane = tid & 63, quad = lane >> 4, lr = lane & 15;
  const int bm = blockIdx.x * 128, bn = blockIdx.y * 128;
  const int wm = (wave >> 1) * 64, wn = (wave & 1) * 64;

  f32x4 acc[4][4] = {};

  const bf16_t* Ag;
  size_t strideA64;  // address delta for +64 rows
  if (MODE == 0) {
    Ag = A + (size_t)(bm + (tid >> 2)) * K + (tid & 3) * 8;
    strideA64 = (size_t)64 * K;
  } else {
    const int rr = bm + (tid >> 2);
    const int bidx = rr >> 10, seq = rr & 1023;
    Ag = A + ((size_t)bidx * 24 * 1024 + seq) * 32 + (tid & 3) * 8;
    strideA64 = (size_t)64 * 32;  // +64 seq rows, same batch
  }
  const bf16_t* Bg = Bw + (size_t)(bn + (tid >> 2)) * K + (tid & 3) * 8;
  const size_t strideB64 = (size_t)64 * K;

  auto stage = [&](int k0, int sel) {
    const size_t aoff = (MODE == 0) ? (size_t)k0 : (size_t)(k0 >> 5) * 32768;
    g2l16(Ag + aoff, &As[sel][tid * 8]);
    g2l16(Ag + strideA64 + aoff, &As[sel][tid * 8 + 2048]);
    g2l16(Bg + k0, &Bs[sel][tid * 8]);
    g2l16(Bg + strideB64 + k0, &Bs[sel][tid * 8 + 2048]);
  };

  const int NT = K >> 5;
  stage(0, 0);
  __syncthreads();  // drain initial staging
  for (int t = 0; t < NT; ++t) {
    const int sel = t & 1;
    if (t + 1 < NT) stage((t + 1) * 32, sel ^ 1);  // prefetch next K-step
    bf16x8 af[4], bfr[4];
#pragma unroll
    for (int i = 0; i < 4; ++i)
      af[i] = *(const bf16x8*)(&As[sel][(wm + i * 16 + lr) * 32 + quad * 8]);
#pragma unroll
    for (int j = 0; j < 4; ++j)
      bfr[j] = *(const bf16x8*)(&Bs[sel][(wn + j * 16 + lr) * 32 + quad * 8]);
#pragma unroll
    for (int i = 0; i < 4; ++i)
#pragma unroll
      for (int j = 0; j < 4; ++j)
        acc[i][j] = MFMA16(bfr[j], af[i], acc[i][j]);  // SWAPPED: C^T fragment
    __syncthreads();  // drains prefetch vmcnt + this tile's lgkm; releases sel
  }

#pragma unroll
  for (int j = 0; j < 4; ++j) {
    const int col0 = bn + wn + j * 16 + quad * 4;   // 4 consecutive cols
    const float4 bb = *(const float4*)(bias + col0);
#pragma unroll
    for (int i = 0; i < 4; ++i) {
      const int row = bm + wm + i * 16 + lr;
      const float v0 = acc[i][j][0] + bb.x, v1 = acc[i][j][1] + bb.y;
      const float v2 = acc[i][j][2] + bb.z, v3 = acc[i][j][3] + bb.w;
      if (MODE == 1) {
        float4 o = {v0, v1, v2, v3};
        *(float4*)(Cout + (size_t)row * N + col0) = o;
      } else {
        const int b = row >> 10, seq = row & 1023;
        const int head = col0 / 96, w0 = col0 % 96;  // region wave-uniform
        const int bh = b * 24 + head;
        if (w0 < 32) {
          const float sc = 0.17677669529663687f;
          bf16x4 q4;
          q4[0] = (bf16_t)(v0 * sc); q4[1] = (bf16_t)(v1 * sc);
          q4[2] = (bf16_t)(v2 * sc); q4[3] = (bf16_t)(v3 * sc);
          *(bf16x4*)(Qb + ((size_t)bh * 1024 + seq) * 32 + w0) = q4;
        } else if (w0 < 64) {
          bf16x4 k4;
          k4[0] = (bf16_t)v0; k4[1] = (bf16_t)v1;
          k4[2] = (bf16_t)v2; k4[3] = (bf16_t)v3;
          *(bf16x4*)(Kb + ((size_t)bh * 1024 + seq) * 32 + (w0 - 32)) = k4;
        } else {
          // direct transposed V store: Vtb[bh][d][seq]
          bf16_t* vp = Vtb + ((size_t)bh * 32 + (w0 - 64)) * 1024 + seq;
          vp[0] = (bf16_t)v0;
          vp[1024] = (bf16_t)v1;
          vp[2048] = (bf16_t)v2;
          vp[3072] = (bf16_t)v3;
        }
      }
    }
  }
}

// ---------------- flash attention v15 (R8/R9-verified config) ----------------
// Occupancy ledger: (256,8) spill [R1], (256,6) spill [R3], (256,5)
// allocator-squeeze VGPR 56->44 + occupancy DIDN'T rise, -11% [R10].
// (256,4) / VGPR 56 is this kernel's fixed point. Knob retired.
__global__ __launch_bounds__(256, 4) void attn_flash(
    const bf16_t* __restrict__ Qb, const bf16_t* __restrict__ Kb,
    const bf16_t* __restrict__ Vtb, const bf16_t* __restrict__ relp,
    bf16_t* __restrict__ Ob) {
  __shared__ bf16_t Ks[2][128 * 32];
  __shared__ bf16_t Vs[2][32 * 128];

  const int tid = threadIdx.x;
  const int wave = tid >> 6, lane = tid & 63, quad = lane >> 4, lr = lane & 15;

  const int flat = blockIdx.x;
  const int xcd = flat & 7, slot = flat >> 3;
  const int pair = xcd + 8 * (slot >> 4);   // 0..191; same pair -> same XCD
  const int qi = slot & 15;
  const int b = pair / 24, h = pair % 24;
  const int bh = b * 24 + h;
  const int q0 = qi * 64 + wave * 16;
  const float LOG2E = 1.44269504f;

  const bf16x8 qf = *(const bf16x8*)(Qb + ((size_t)bh * 1024 + q0 + lr) * 32 + quad * 8);

  bf16x8 onesf;
#pragma unroll
  for (int i = 0; i < 8; ++i) onesf[i] = (bf16_t)1.0f;

  f32x4 o_acc[2] = {};
  f32x4 l_acc = {};  // row-sum accumulator: l = P * ones (MFMA pipe)

  // permuted bias v2: block = h*64 + (qi*4 + wave); per-lane 4x bf16x8
  const bf16_t* relg = relp + (size_t)(h * 64 + qi * 4 + wave) * 16384 + lane * 8;
  const bf16_t* Kg = Kb + (size_t)bh * 1024 * 32;
  const bf16_t* Vg = Vtb + (size_t)bh * 32 * 1024;

  // stage K-tile + Vt-tile for k-window [kt, kt+128) into buffer sel
  auto stageKV = [&](int kt, int sel) {
#pragma unroll
    for (int p = 0; p < 2; ++p) {
      const int cid = p * 256 + tid;           // 0..511
      const int krow = cid >> 2, kc = cid & 3;
      const int ks_ = (krow >> 1) & 3;
      g2l16(Kg + ((size_t)(kt + krow) * 32 + ((kc ^ ks_) * 8)), &Ks[sel][cid * 8]);
      const int vd = cid >> 4, vc = cid & 15;
      g2l16(Vg + ((size_t)vd * 1024 + kt + ((vc ^ (vd & 7)) * 8)), &Vs[sel][cid * 8]);
    }
  };

  auto body = [&](int kt, int sel) {
    // bias tile: 4x bf16x8, 1KB contiguous per wave-load
    bf16x8 bb[4];
    const bf16_t* rb = relg + (size_t)(kt >> 7) * 2048;
#pragma unroll
    for (int i = 0; i < 4; ++i) bb[i] = *(const bf16x8*)(rb + i * 512);

    // S^T = K Q^T (swapped): lane holds q = lr, k = jt*16 + quad*4 + r
    f32x4 s[8];
    const f32x4 zz = {0.f, 0.f, 0.f, 0.f};
    const int kcs = quad ^ ((lr >> 1) & 3);   // staged-K chunk swizzle
#pragma unroll
    for (int jt = 0; jt < 8; ++jt) {
      const bf16x8 kf = *(const bf16x8*)&Ks[sel][(jt * 16 + lr) * 32 + kcs * 8];
      s[jt] = MFMA16(kf, qf, zz);
    }
    // P = exp2(S*log2e + bias_prescaled); bias (jt,r) = bb[jt>>1][(jt&1)*4+r]
#pragma unroll
    for (int jt = 0; jt < 8; ++jt)
#pragma unroll
      for (int r = 0; r < 4; ++r)
        s[jt][r] = EXP2(fmaf(s[jt][r], LOG2E, (float)bb[jt >> 1][(jt & 1) * 4 + r]));

    // P -> PV A-frag entirely in registers (permlane 4x4 quad-transpose)
#pragma unroll
    for (int ks = 0; ks < 4; ++ks) {
      bf16x4 pe, po;
#pragma unroll
      for (int r = 0; r < 4; ++r) {
        pe[r] = (bf16_t)s[2 * ks][r];
        po[r] = (bf16_t)s[2 * ks + 1][r];
      }
      u32x2 ue = __builtin_bit_cast(u32x2, pe);
      u32x2 uo = __builtin_bit_cast(u32x2, po);
      u32 d0 = ue[0], d1 = ue[1], d2 = uo[0], d3 = uo[1];
      PERMSWAP(d0, d2);
      PERMSWAP(d1, d3);
      u32x4 uf = {d0, d1, d2, d3};
      const bf16x8 pf = __builtin_bit_cast(bf16x8, uf);

      l_acc = MFMA16(pf, onesf, l_acc);
#pragma unroll
      for (int nt = 0; nt < 2; ++nt) {
        const int d = nt * 16 + lr;
        const int vc = (ks * 4 + quad) ^ (d & 7);
        const bf16x8 vf = *(const bf16x8*)&Vs[sel][d * 128 + vc * 8];
        o_acc[nt] = MFMA16(pf, vf, o_acc[nt]);
      }
    }
  };

  stageKV(0, 0);
  __syncthreads();  // drains staging vmcnt
  for (int t = 0; t < 8; ++t) {
    const int sel = t & 1;
    if (t < 7) stageKV((t + 1) * 128, sel ^ 1);  // prefetch next tile
    body(t * 128, sel);                          // compute current tile
    __syncthreads();
  }

  // write O head-major [bh][seq][32] — packed stores
  float inv_l[4];
#pragma unroll
  for (int r = 0; r < 4; ++r) inv_l[r] = 1.0f / l_acc[r];
#pragma unroll
  for (int nt = 0; nt < 2; ++nt)
#pragma unroll
    for (int r = 0; r < 4; ++r) {
      const int seq = q0 + quad * 4 + r;
      Ob[((size_t)bh * 1024 + seq) * 32 + nt * 16 + lr] = (bf16_t)(o_acc[nt][r] * inv_l[r]);
    }
}

extern "C" void kernel_launch(void* const* d_in, const int* in_sizes, int n_in,
                              void* d_out, int out_size, void* d_ws, size_t ws_size,
                              hipStream_t stream) {
  const float* x = (const float*)d_in[0];
  const float* rel = (const float*)d_in[1];
  const float* Wqkv = (const float*)d_in[2];
  const float* bqkv = (const float*)d_in[3];
  const float* Wproj = (const float*)d_in[4];
  const float* bproj = (const float*)d_in[5];
  float* out = (float*)d_out;

  char* ws = (char*)d_ws;
  bf16_t* xb = (bf16_t*)ws;     ws += (size_t)8192 * 768 * 2;
  bf16_t* wqkvb = (bf16_t*)ws;  ws += (size_t)2304 * 768 * 2;
  bf16_t* wprojb = (bf16_t*)ws; ws += (size_t)768 * 768 * 2;
  bf16_t* Qb = (bf16_t*)ws;     ws += (size_t)192 * 1024 * 32 * 2;
  bf16_t* Kb = (bf16_t*)ws;     ws += (size_t)192 * 1024 * 32 * 2;
  bf16_t* Vtb = (bf16_t*)ws;    ws += (size_t)192 * 1024 * 32 * 2;
  bf16_t* relp = (bf16_t*)ws;   ws += (size_t)24 * 1024 * 1024 * 2;
  bf16_t* Ob = xb;  // xb dead after QKV GEMM; O is head-major [bh][seq][32]

  cvt_f32_bf16<<<(8192 * 768 / 4 + 255) / 256, 256, 0, stream>>>(x, xb, 8192 * 768 / 4);
  cvt_f32_bf16<<<(2304 * 768 / 4 + 255) / 256, 256, 0, stream>>>(Wqkv, wqkvb, 2304 * 768 / 4);
  cvt_f32_bf16<<<(768 * 768 / 4 + 255) / 256, 256, 0, stream>>>(Wproj, wprojb, 768 * 768 / 4);
  permute_rel<<<dim3(24 * 64), 256, 0, stream>>>(rel, relp);

  gemm_bt<0><<<dim3(64, 18), 256, 0, stream>>>(xb, wqkvb, bqkv, nullptr,
                                               Qb, Kb, Vtb, 8192, 2304, 768);
  attn_flash<<<dim3(3072), 256, 0, stream>>>(Qb, Kb, Vtb, relp, Ob);
  gemm_bt<1><<<dim3(64, 6), 256, 0, stream>>>(Ob, wprojb, bproj, out,
                                              nullptr, nullptr, nullptr, 8192, 768, 768);
}